// Round 7
// baseline (194.340 us; speedup 1.0000x reference)
//
#include <hip/hip_runtime.h>

// Correlation via banded bf16 MFMA GEMM, v12 = v5 EXACTLY + a second
// (idempotent) transpose launch as a timing probe.
// out[b, di*21+dj, i, j] = sum_c x1p[b,c,i+di-10,j+dj-10] * x2[b,c,i,j]
//
// WHY THE PROBE: six structural rewrites of corr_mfma (v6..v11) all failed to
// beat v5's 184.9 us total. The decomposition "fill 67.8 + corr ~62 +
// transpose+gaps ~55" has never had the transpose directly measured (it hides
// below the top-5 fill cutoff at ~67.5 us); subtraction-based estimates carry
// +-10 us noise. transpose is launched TWICE with byte-identical writes
// (pure function of x1 -> idempotent, no hazard):
//   T = total_v12 - 184.9  (one unknown, one equation, +-3 us)
// and if T > 67 us the dispatch surfaces in top-5 with full counters.
// Branch plan: T ~ 15 -> ~40 us is inter-dispatch overhead -> reduce launch
// count next round. T ~ 50 -> transpose is 4x over its 12 us roofline ->
// rewrite it (H-split occupancy, keep 256B write segments; v9's channel-split
// 128B-write trap avoided).
//
// Pass 1 (transpose_x1): v5 verbatim. Pass 2 (corr_mfma): v5 verbatim
// (5-buffer rolling window, one __syncthreads per di step, 2 blocks/CU).

#define NB 4
#define NC 128
#define NW 128
#define NH 128
#define DW 21
#define PAD 10
#define NROW_T 148   // NW + 2*PAD
#define NCOL_T 160   // padded cols (148..159 zero)
#define NCH 441
#define PS 37        // patch col stride (col-major [16 cols][37 rows])
#define SCOLS 52     // slice cols: 32 out + 20 halo
#define SUS (SCOLS * NC)        // 6656 ushorts = 13,312 B
#define ROW_US (NCOL_T * NC)    // 20480 ushorts per full x1T row

typedef __attribute__((ext_vector_type(8))) short short8;   // 8 bf16
typedef __attribute__((ext_vector_type(4))) float float4v;  // 4 fp32

__device__ inline ushort f2bf(float f) {
    union { float f; uint u; } v; v.f = f;
    const uint u = v.u;
    return (ushort)((u + 0x7fffu + ((u >> 16) & 1u)) >> 16);  // RNE
}

__device__ inline void async_copy16(const void* g, void* l) {
    __builtin_amdgcn_global_load_lds(
        (const __attribute__((address_space(1))) void*)g,
        (__attribute__((address_space(3))) void*)l, 16, 0, 0);
}

// Stage one 13,312 B row slice: 3 full 4 KB rounds + 1 KB tail (wave 0 only).
__device__ inline void stage_row(const ushort* src, ushort* dst, int t) {
    const char* s = (const char*)src;
    char* d = (char*)dst;
    #pragma unroll
    for (int it = 0; it < 3; ++it) {
        const int off = it * 4096 + t * 16;
        async_copy16(s + off, d + off);
    }
    if (t < 64) {
        const int off = 12288 + t * 16;
        async_copy16(s + off, d + off);
    }
}

// One block per (b, padded row r). v5 verbatim.
__global__ __launch_bounds__(256) void transpose_x1(const float* __restrict__ x1,
                                                    ushort* __restrict__ x1T) {
    __shared__ uint tile[128][65];
    const int t = threadIdx.x;
    const int b = blockIdx.x / NROW_T;
    const int r = blockIdx.x % NROW_T;
    const int w = r - PAD;
    const bool inr = (w >= 0 && w < NW);
    if (inr) {
        #pragma unroll
        for (int it = 0; it < 8; ++it) {
            const int u = it * 256 + t;
            const int g4 = u & 31;          // float4 group along h (coalesced)
            const int cp = u >> 5;          // channel pair
            const float4 va = *(const float4*)&x1[(((size_t)b * NC + 2 * cp    ) * NW + w) * NH + g4 * 4];
            const float4 vb = *(const float4*)&x1[(((size_t)b * NC + 2 * cp + 1) * NW + w) * NH + g4 * 4];
            tile[g4 * 4 + 0][cp] = (uint)f2bf(va.x) | ((uint)f2bf(vb.x) << 16);
            tile[g4 * 4 + 1][cp] = (uint)f2bf(va.y) | ((uint)f2bf(vb.y) << 16);
            tile[g4 * 4 + 2][cp] = (uint)f2bf(va.z) | ((uint)f2bf(vb.z) << 16);
            tile[g4 * 4 + 3][cp] = (uint)f2bf(va.w) | ((uint)f2bf(vb.w) << 16);
        }
    }
    __syncthreads();
    #pragma unroll
    for (int it = 0; it < 10; ++it) {
        const int u = it * 256 + t;
        const int cg = u & 15;
        const int col = u >> 4;             // 0..159
        uint4 v = make_uint4(0, 0, 0, 0);
        const int h = col - PAD;
        if (inr && h >= 0 && h < NH) {
            v.x = tile[h][cg * 4 + 0];
            v.y = tile[h][cg * 4 + 1];
            v.z = tile[h][cg * 4 + 2];
            v.w = tile[h][cg * 4 + 3];
        }
        const int chunk = cg ^ (col & 15);  // swizzle for conflict-free pass-2 reads
        *(uint4*)&x1T[(((size_t)b * NROW_T + r) * NCOL_T + col) * NC + chunk * 8] = v;
    }
}

// Block = (b, i-quad, j-quarter), XCD-swizzled. 256 threads = 4 waves = 4 rows.
// v5 verbatim.
__global__ __launch_bounds__(256) void corr_mfma(const ushort* __restrict__ x1T,
                                                 const float* __restrict__ x2,
                                                 float* __restrict__ out) {
    __shared__ ushort win[5][SUS];          // 66,560 B rolling row window
    __shared__ float patch[4][16 * PS];     // 9,472 B

    const int t = threadIdx.x;
    const int wave = t >> 6;                // = row offset 0..3
    const int lane = t & 63;
    const int n16 = lane & 15;
    const int q = lane >> 4;

    // XCD swizzle: hw XCD = blockIdx%8 -> XCD k serves (b = k>>1, ihalf = k&1),
    // 64 slots = 16 i-quads x 4 j-quarters (x1T band ~3.4 MB, fits 4 MB L2).
    const int n = blockIdx.x;
    const int b = (n & 7) >> 1;
    const int ihalf = n & 1;
    const int slot = n >> 3;                // 0..63
    const int iq = ihalf * 16 + (slot >> 2);
    const int jq = slot & 3;
    const int i0 = iq * 4;
    const int col0 = jq * 32;
    const int i = i0 + wave;

    const ushort* xbase = x1T + (size_t)(b * NROW_T) * ROW_US + (size_t)col0 * NC;

    // preload rows i0..i0+3 into buffers 0..3 (buffer = (row - i0) % 5)
    #pragma unroll
    for (int r = 0; r < 4; ++r)
        stage_row(xbase + (size_t)(i0 + r) * ROW_US, win[r], t);

    // B fragments from fp32 x2 (read once per block; lane n=n16, k=q*8+e+32*k4)
    short8 Bf[2][4];
    #pragma unroll
    for (int nt = 0; nt < 2; ++nt) {
        const int jc = col0 + nt * 16 + n16;
        #pragma unroll
        for (int k4 = 0; k4 < 4; ++k4) {
            short8 s;
            #pragma unroll
            for (int e = 0; e < 8; ++e) {
                const int c = k4 * 32 + q * 8 + e;
                s[e] = (short)f2bf(x2[(((size_t)b * NC + c) * NW + i) * NH + jc]);
            }
            Bf[nt][k4] = s;
        }
    }

    __syncthreads();  // preload drained

    float* P = &patch[wave][0];

    for (int di = 0; di < DW; ++di) {
        const ushort* A = win[(di + wave) % 5];  // wave's A-row = i0 + wave + di

        // 16 ds_read_b128 first (tile bases {0,16,32,36})
        short8 Af[4][4];
        #pragma unroll
        for (int k4 = 0; k4 < 4; ++k4) {
            const int kc = q + 4 * k4;
            #pragma unroll
            for (int tl = 0; tl < 4; ++tl) {
                const int base = (tl < 3) ? tl * 16 : 36;
                const int c = base + n16;
                Af[tl][k4] = *(const short8*)&A[c * NC + ((kc ^ (c & 15)) & 15) * 8];
            }
        }

        // prefetch row i0+di+4 into buffer (di+4)%5; covered by MFMA + epilogue.
        if (di < DW - 1)
            stage_row(xbase + (size_t)(i0 + di + 4) * ROW_US, win[(di + 4) % 5], t);

        float4v a00 = {0.f,0.f,0.f,0.f}, a01 = {0.f,0.f,0.f,0.f}, a02 = {0.f,0.f,0.f,0.f};
        float4v a10 = {0.f,0.f,0.f,0.f}, a11 = {0.f,0.f,0.f,0.f}, a12 = {0.f,0.f,0.f,0.f};
        #pragma unroll
        for (int k4 = 0; k4 < 4; ++k4) {
            a00 = __builtin_amdgcn_mfma_f32_16x16x32_bf16(Af[0][k4], Bf[0][k4], a00, 0, 0, 0);
            a01 = __builtin_amdgcn_mfma_f32_16x16x32_bf16(Af[1][k4], Bf[0][k4], a01, 0, 0, 0);
            a02 = __builtin_amdgcn_mfma_f32_16x16x32_bf16(Af[2][k4], Bf[0][k4], a02, 0, 0, 0);
            a10 = __builtin_amdgcn_mfma_f32_16x16x32_bf16(Af[1][k4], Bf[1][k4], a10, 0, 0, 0);
            a11 = __builtin_amdgcn_mfma_f32_16x16x32_bf16(Af[2][k4], Bf[1][k4], a11, 0, 0, 0);
            a12 = __builtin_amdgcn_mfma_f32_16x16x32_bf16(Af[3][k4], Bf[1][k4], a12, 0, 0, 0);
        }

        // Epilogue: per nt, band-extract via per-wave col-major patch P[n*37 + r].
        #pragma unroll
        for (int nt = 0; nt < 2; ++nt) {
            const float4v va = nt ? a10 : a00;  // rel rows 0..15
            const float4v vb = nt ? a11 : a01;  // rel rows 16..31
            const float4v vc = nt ? a12 : a02;  // nt0 q==0 / nt1 q==3 -> rows 32..35
            #pragma unroll
            for (int reg = 0; reg < 4; ++reg) {
                P[n16 * PS + q * 4 + reg]      = va[reg];
                P[n16 * PS + 16 + q * 4 + reg] = vb[reg];
            }
            if (q == (nt ? 3 : 0)) {
                #pragma unroll
                for (int reg = 0; reg < 4; ++reg)
                    P[n16 * PS + 32 + reg] = vc[reg];
            }
            #pragma unroll
            for (int it2 = 0; it2 < 2; ++it2) {
                const int u = it2 * 64 + lane;
                if (u < 84) {
                    const int dj = u >> 2;
                    const int jj = (u & 3) * 4;
                    float4v v;
                    #pragma unroll
                    for (int p = 0; p < 4; ++p)
                        v[p] = P[(jj + p) * (PS + 1) + dj];  // col jj+p, row jj+p+dj
                    *(float4v*)&out[(((size_t)(b * NCH + di * DW + dj)) * NW + i) * NH
                                    + col0 + nt * 16 + jj] = v;
                }
            }
        }

        __syncthreads();  // single barrier: patch reuse + prefetch drain (covered)
    }
}

extern "C" void kernel_launch(void* const* d_in, const int* in_sizes, int n_in,
                              void* d_out, int out_size, void* d_ws, size_t ws_size,
                              hipStream_t stream) {
    const float* x1 = (const float*)d_in[0];
    const float* x2 = (const float*)d_in[1];
    float* out = (float*)d_out;
    ushort* x1T = (ushort*)d_ws;  // 4*148*160*128*2 = 24,248,320 B
    // PROBE: transpose launched twice (idempotent, byte-identical writes).
    // T = total_v12 - total_v5(184.9us). Remove the duplicate next round.
    transpose_x1<<<dim3(NB * NROW_T), dim3(256), 0, stream>>>(x1, x1T);
    transpose_x1<<<dim3(NB * NROW_T), dim3(256), 0, stream>>>(x1, x1T);
    corr_mfma<<<dim3(NB * 32 * 4), dim3(256), 0, stream>>>(x1T, x2, out);
}